// Round 5
// baseline (429.838 us; speedup 1.0000x reference)
//
#include <hip/hip_runtime.h>
#include <math.h>

// TemporalEncoder: out[t, b, d] = (t == floor(sigmoid(x[b,d]) * (T-1))) ? 1 : 0
// B=256, D=4096, T=100. Output 419 MB fp32 -> pure write-BW bound (~67 us at
// 6.3 TB/s). The timed window also contains a 1.64 GB harness poison fill
// (~265 us @ 6.2 TB/s, visible in rocprof top-5) which no kernel change can
// remove. Budget above that: write 419 MB + read 4 MB.
//
// R1: per-element t-loop -> scattered 1KB bursts (~159 us model-A).
// R2: one-shot coalesced, 1 store/thread -> best total (401).
// R3: 64B-per-lane grid-stride -> uncoalesced stores (worst, 455).
// R4: persistent 2-pass -> 423; pass-2 slower than expected or constant
//     harness overhead masks it (model ambiguity).
// R5: single FUSED fill-shaped kernel: sigmoid computed once in-register
//     from x (no ws, no 2nd dispatch), ci loop-invariant, 32-bit pointer
//     increments, nontemporal 16B/lane coalesced stores, 50 iters/thread.

typedef __attribute__((ext_vector_type(4))) float f32x4;

__device__ __forceinline__ float sigmoidf(float x) {
    return 1.0f / (1.0f + expf(-x));  // 0-ulp match vs np ref (R1 absmax=0)
}

// Fast path: n = 4 * 2^lgp4, gridDim.x*256 = S threads, S a multiple of
// 2^lgp4 (plane size in float4 units). Thread owns float4-column ci = gid &
// (2^lgp4 - 1), loop-invariant; writes planes t = t0, t0+tstep, ...
__global__ __launch_bounds__(256) void temporal_onehot_fused(
    const float* __restrict__ x, float* __restrict__ out,
    int lgp4, int T, float tm1) {
    const unsigned int S = gridDim.x * 256u;
    const unsigned int gid = blockIdx.x * 256u + threadIdx.x;
    const unsigned int mask = (1u << lgp4) - 1u;
    const unsigned int ci = gid & mask;
    const unsigned int t0 = gid >> lgp4;
    const unsigned int tstep = S >> lgp4;

    const f32x4 v = *reinterpret_cast<const f32x4*>(x + (size_t)ci * 4);
    const int s0 = (int)(sigmoidf(v.x) * tm1);
    const int s1 = (int)(sigmoidf(v.y) * tm1);
    const int s2 = (int)(sigmoidf(v.z) * tm1);
    const int s3 = (int)(sigmoidf(v.w) * tm1);

    f32x4* p = reinterpret_cast<f32x4*>(out) + gid;
    for (unsigned int t = t0; t < (unsigned int)T; t += tstep) {
        f32x4 o;
        o.x = ((int)t == s0) ? 1.0f : 0.0f;
        o.y = ((int)t == s1) ? 1.0f : 0.0f;
        o.z = ((int)t == s2) ? 1.0f : 0.0f;
        o.w = ((int)t == s3) ? 1.0f : 0.0f;
        __builtin_nontemporal_store(o, p);
        p += S;
    }
}

// Fallback (non-pow2 n etc.): fused recompute, one float4/thread, 2D grid.
__global__ __launch_bounds__(256) void fused_onehot_kernel(
    const float* __restrict__ x, float* __restrict__ out, int n, float tm1) {
    const int t = blockIdx.y;
    const int e = (blockIdx.x * 256 + threadIdx.x) * 4;
    if (e + 3 < n) {
        f32x4 v = *reinterpret_cast<const f32x4*>(x + e);
        f32x4 o;
        o.x = ((int)(sigmoidf(v.x) * tm1) == t) ? 1.0f : 0.0f;
        o.y = ((int)(sigmoidf(v.y) * tm1) == t) ? 1.0f : 0.0f;
        o.z = ((int)(sigmoidf(v.z) * tm1) == t) ? 1.0f : 0.0f;
        o.w = ((int)(sigmoidf(v.w) * tm1) == t) ? 1.0f : 0.0f;
        *reinterpret_cast<f32x4*>(out + (size_t)t * n + e) = o;
    } else {
        for (int i = e; i < n; ++i)
            out[(size_t)t * n + i] = ((int)(sigmoidf(x[i]) * tm1) == t) ? 1.0f : 0.0f;
    }
}

extern "C" void kernel_launch(void* const* d_in, const int* in_sizes, int n_in,
                              void* d_out, int out_size, void* d_ws, size_t ws_size,
                              hipStream_t stream) {
    const float* x = (const float*)d_in[0];
    float* out = (float*)d_out;
    const int n = in_sizes[0];        // B*D = 1048576 = 2^20
    const int T = out_size / n;       // 100
    const float tm1 = (float)(T - 1);

    const bool pow2 = (n & (n - 1)) == 0 && n >= 16;
    const int blocks = 2048;                        // 8 blocks/CU, full occupancy
    const unsigned int S = (unsigned int)blocks * 256u;  // 2^19 threads
    int lgp4 = 0;
    if (pow2) { while ((4 << lgp4) < n) ++lgp4; }   // n = 4 * 2^lgp4 -> 18
    const unsigned int plane_f4 = 1u << lgp4;
    const bool fast = pow2 && (4 << lgp4) == n &&
                      S >= plane_f4 && (S % plane_f4) == 0;
    if (fast) {
        temporal_onehot_fused<<<blocks, 256, 0, stream>>>(x, out, lgp4, T, tm1);
    } else {
        const int blocks_x = ((n + 3) / 4 + 255) / 256;
        dim3 grid(blocks_x, T);
        fused_onehot_kernel<<<grid, 256, 0, stream>>>(x, out, n, tm1);
    }
}

// Round 6
// 410.718 us; speedup vs baseline: 1.0466x; 1.0466x over previous
//
#include <hip/hip_runtime.h>
#include <math.h>

// TemporalEncoder: out[t, b, d] = (t == floor(sigmoid(x[b,d]) * (T-1))) ? 1 : 0
// B=256, D=4096, T=100. Output 419 MB fp32 -> pure write-BW bound; kernel
// floor = 423 MB / 6.3 TB/s ~ 67 us. The timed window additionally carries
// fixed harness cost: 1.678 GB poison fill (~262 us, in rocprof top-5 every
// round) + d_in restore/sync (~65 us) -> structural total floor ~395 us.
//
// Round history (total us): R1 per-elem t-loop 426 | R2 2-pass one-shot 401
// (BEST) | R3 64B/lane grid-stride 455 (uncoalesced) | R4 persistent 2-pass
// 423 | R5 fused persistent + nt stores 430. Lesson: one-shot block-churn
// with 1KB/wave coalesced stores and x-major dispatch order beats persistent
// grid-stride here; sophistication bought nothing.
//
// R6 = R2 minus its fat: single fused one-shot kernel. 2D grid (x: plane
// chunks, y: t). One coalesced float4 store per thread; sigmoid recomputed
// in-register per plane (redundant x100 but VALU-overlapped; x reads are
// L2/LLC-hit after first plane). No ws, no second dispatch.

typedef __attribute__((ext_vector_type(4))) float f32x4;

__device__ __forceinline__ float sigmoidf(float x) {
    return 1.0f / (1.0f + expf(-x));  // 0-ulp match vs np ref (R1 absmax=0)
}

__global__ __launch_bounds__(256) void fused_onehot_kernel(
    const float* __restrict__ x, float* __restrict__ out, int n, float tm1) {
    const int t = blockIdx.y;
    const int e = (blockIdx.x * 256 + threadIdx.x) * 4;
    if (e + 3 < n) {
        f32x4 v = *reinterpret_cast<const f32x4*>(x + e);
        f32x4 o;
        o.x = ((int)(sigmoidf(v.x) * tm1) == t) ? 1.0f : 0.0f;
        o.y = ((int)(sigmoidf(v.y) * tm1) == t) ? 1.0f : 0.0f;
        o.z = ((int)(sigmoidf(v.z) * tm1) == t) ? 1.0f : 0.0f;
        o.w = ((int)(sigmoidf(v.w) * tm1) == t) ? 1.0f : 0.0f;
        *reinterpret_cast<f32x4*>(out + (size_t)t * n + e) = o;
    } else {
        for (int i = e; i < n; ++i)
            out[(size_t)t * n + i] = ((int)(sigmoidf(x[i]) * tm1) == t) ? 1.0f : 0.0f;
    }
}

extern "C" void kernel_launch(void* const* d_in, const int* in_sizes, int n_in,
                              void* d_out, int out_size, void* d_ws, size_t ws_size,
                              hipStream_t stream) {
    const float* x = (const float*)d_in[0];
    float* out = (float*)d_out;
    const int n = in_sizes[0];        // B*D = 1048576
    const int T = out_size / n;       // 100
    const float tm1 = (float)(T - 1);

    const int blocks_x = ((n + 3) / 4 + 255) / 256;   // 1024
    dim3 grid(blocks_x, T);
    fused_onehot_kernel<<<grid, 256, 0, stream>>>(x, out, n, tm1);
}